// Round 3
// baseline (276.900 us; speedup 1.0000x reference)
//
#include <hip/hip_runtime.h>

#define SEQ_T 2048
#define HDIM  128
#define NB    16

typedef __attribute__((ext_vector_type(8))) short short8;      // 8 bf16 (4 VGPRs)
typedef __attribute__((ext_vector_type(4))) float float4v;
typedef __attribute__((ext_vector_type(4))) unsigned int uint4v;

// native 2^x (v_exp_f32)
#define EXP2F(x) __builtin_amdgcn_exp2f(x)

// round-half-up fp32 -> bf16, pack pair into one u32
__device__ __forceinline__ unsigned int bfpack2(float a, float b) {
  unsigned int ua = __builtin_bit_cast(unsigned int, a);
  unsigned int ub = __builtin_bit_cast(unsigned int, b);
  return ((ua + 0x8000u) >> 16) | ((ub + 0x8000u) & 0xFFFF0000u);
}
__device__ __forceinline__ unsigned short f2bf(float a) {
  return (unsigned short)((__builtin_bit_cast(unsigned int, a) + 0x8000u) >> 16);
}

// 16-lane butterfly reductions via DPP (VALU-rate, no LDS pipe):
// quad_perm(1,0,3,2)=0xB1 (xor1), quad_perm(2,3,0,1)=0x4E (xor2),
// row_half_mirror=0x141 (pairs across quads of 8), row_mirror=0x140 (across halves of 16)
__device__ __forceinline__ float dpp_max16(float x) {
  int t;
  t = __builtin_amdgcn_mov_dpp(__builtin_bit_cast(int, x), 0xB1, 0xF, 0xF, true);
  x = fmaxf(x, __builtin_bit_cast(float, t));
  t = __builtin_amdgcn_mov_dpp(__builtin_bit_cast(int, x), 0x4E, 0xF, 0xF, true);
  x = fmaxf(x, __builtin_bit_cast(float, t));
  t = __builtin_amdgcn_mov_dpp(__builtin_bit_cast(int, x), 0x141, 0xF, 0xF, true);
  x = fmaxf(x, __builtin_bit_cast(float, t));
  t = __builtin_amdgcn_mov_dpp(__builtin_bit_cast(int, x), 0x140, 0xF, 0xF, true);
  x = fmaxf(x, __builtin_bit_cast(float, t));
  return x;
}
__device__ __forceinline__ float dpp_sum16(float x) {
  int t;
  t = __builtin_amdgcn_mov_dpp(__builtin_bit_cast(int, x), 0xB1, 0xF, 0xF, true);
  x += __builtin_bit_cast(float, t);
  t = __builtin_amdgcn_mov_dpp(__builtin_bit_cast(int, x), 0x4E, 0xF, 0xF, true);
  x += __builtin_bit_cast(float, t);
  t = __builtin_amdgcn_mov_dpp(__builtin_bit_cast(int, x), 0x141, 0xF, 0xF, true);
  x += __builtin_bit_cast(float, t);
  t = __builtin_amdgcn_mov_dpp(__builtin_bit_cast(int, x), 0x140, 0xF, 0xF, true);
  x += __builtin_bit_cast(float, t);
  return x;
}

// x layout: [B, T, 384] with k = [0,128), q = [128,256), v = [256,384)
// Block: 512 threads = 8 waves. Waves 0-3: q-tiles 0-3, EVEN kv tiles.
// Waves 4-7: q-tiles 0-3, ODD kv tiles. End-of-loop merge via LDS overlay.
__global__ __launch_bounds__(512, 6) void attn_causal_kernel(const float* __restrict__ x,
                                                             float* __restrict__ out) {
  const int b    = blockIdx.y;
  const int qblk = (int)gridDim.x - 1 - (int)blockIdx.x;  // longest blocks dispatch first
  const int qb0  = qblk << 6;                             // 64 q-rows per block
  const int tid  = threadIdx.x;
  const int wave = tid >> 6;
  const int lane = tid & 63;
  const int low  = lane & 15;
  const int quad = lane >> 4;
  const int qt   = wave & 3;                              // q-tile within block
  const int half = wave >> 2;                             // kv parity
  const int q0   = qb0 + (qt << 4);

  // staging layout (48128 B total -> 3 blocks/CU by LDS):
  __shared__ __align__(16) unsigned char smem[48128];
  unsigned short* Ks = (unsigned short*)smem;             // [2][32*136] bf16, 17408 B
  unsigned short* Vt = (unsigned short*)(smem + 17408);   // [2][128*40] bf16 transposed, 20480 B
  unsigned short* Ps = (unsigned short*)(smem + 37888);   // [8][16*40] bf16, 10240 B
  // merge overlay (only used after the loop, after a barrier):
  float* Om = (float*)smem;                               // [4][16*132] fp32, 33792 B
  float* Ml = (float*)(smem + 33792);                     // [4][32] m|l, 512 B

  const float* xb = x + (size_t)b * (SEQ_T * 3 * HDIM);

  // ---- Q fragments, pre-scaled by 128^-0.5 * log2(e) so softmax uses exp2 ----
  const float qs = 0.08838834764831845f * 1.4426950408889634f;
  short8 qa[4];
  {
    const float* qrow = xb + (size_t)(q0 + low) * 384 + 128;
    for (int kc = 0; kc < 4; ++kc) {
      float4v f0 = *(const float4v*)(qrow + kc * 32 + quad * 8);
      float4v f1 = *(const float4v*)(qrow + kc * 32 + quad * 8 + 4);
      uint4v u = { bfpack2(f0[0] * qs, f0[1] * qs), bfpack2(f0[2] * qs, f0[3] * qs),
                   bfpack2(f1[0] * qs, f1[1] * qs), bfpack2(f1[2] * qs, f1[3] * qs) };
      qa[kc] = __builtin_bit_cast(short8, u);
    }
  }

  float4v accv[8];
  for (int i = 0; i < 8; ++i) accv[i] = (float4v){0.f, 0.f, 0.f, 0.f};
  float m_i[4] = {-1e30f, -1e30f, -1e30f, -1e30f};
  float l_i[4] = {0.f, 0.f, 0.f, 0.f};

  const int nsuper = qblk + 1;            // 64 kv rows (2 tiles) per super-iteration
  for (int s = 0; s < nsuper; ++s) {
    const int r0 = s << 6;
    __syncthreads();

    // ---- stage K: 64 rows x 128, fp32->bf16, 512 threads x 4 float4 ----
    for (int i = 0; i < 4; ++i) {
      int f   = tid + (i << 9);
      int row = f >> 5;                   // 0..63
      int c4  = (f & 31) << 2;
      float4v kf = *(const float4v*)(xb + (size_t)(r0 + row) * 384 + c4);
      *(uint2*)&Ks[(row >> 5) * 4352 + (row & 31) * 136 + c4] =
          make_uint2(bfpack2(kf[0], kf[1]), bfpack2(kf[2], kf[3]));
    }
    // ---- stage V transposed: thread owns 4kv x 4d block ----
    {
      int kb  = tid >> 5;                 // 0..15 (kv block of 4)
      int db  = tid & 31;                 // d block of 4
      int til = kb >> 3, kbl = kb & 7;
      const float* vbase = xb + (size_t)(r0 + 4 * kb) * 384 + 256 + 4 * db;
      float4v v0 = *(const float4v*)(vbase);
      float4v v1 = *(const float4v*)(vbase + 384);
      float4v v2 = *(const float4v*)(vbase + 768);
      float4v v3 = *(const float4v*)(vbase + 1152);
      unsigned short* vt = Vt + til * 5120;
      for (int j = 0; j < 4; ++j) {
        int d  = 4 * db + j;
        int pb = ((kbl >> 1) + (d >> 3)) & 3;   // 16B-block XOR swizzle
        *(uint2*)&vt[d * 40 + pb * 8 + (kbl & 1) * 4] =
            make_uint2(bfpack2(v0[j], v1[j]), bfpack2(v2[j], v3[j]));
      }
    }
    __syncthreads();

    const int c0 = r0 + (half << 5);
    if (c0 <= q0 + 15) {                  // wave-uniform causal skip
      const unsigned short* Ksp = Ks + half * 4352;
      const unsigned short* Vtp = Vt + half * 5120;

      // ---- S = Q K^T (pre-scaled): two 16-col tiles, K=128 = 4 mfma each ----
      float4v s0 = {0.f,0.f,0.f,0.f}, s1 = {0.f,0.f,0.f,0.f};
      for (int kc = 0; kc < 4; ++kc) {
        short8 kf0 = *(const short8*)&Ksp[low * 136 + kc * 32 + quad * 8];
        short8 kf1 = *(const short8*)&Ksp[(16 + low) * 136 + kc * 32 + quad * 8];
        s0 = __builtin_amdgcn_mfma_f32_16x16x32_bf16(qa[kc], kf0, s0, 0, 0, 0);
        s1 = __builtin_amdgcn_mfma_f32_16x16x32_bf16(qa[kc], kf1, s1, 0, 0, 0);
      }
      // ---- causal mask only on diagonal tiles (C-layout: col=lane&15, row=quad*4+r) ----
      if (c0 + 31 > q0) {
        for (int r = 0; r < 4; ++r) {
          int qrow = q0 + quad * 4 + r;
          s0[r] = (c0 + low      <= qrow) ? s0[r] : -1e30f;
          s1[r] = (c0 + 16 + low <= qrow) ? s1[r] : -1e30f;
        }
      }
      // ---- online softmax in exp2 domain, DPP reductions ----
      float rmax[4], alpha[4];
      for (int r = 0; r < 4; ++r) rmax[r] = dpp_max16(fmaxf(s0[r], s1[r]));
      for (int r = 0; r < 4; ++r) {
        float mn = fmaxf(m_i[r], rmax[r]);
        alpha[r] = EXP2F(m_i[r] - mn);
        m_i[r]   = mn;
      }
      for (int r = 0; r < 4; ++r) {
        s0[r] = EXP2F(s0[r] - m_i[r]);
        s1[r] = EXP2F(s1[r] - m_i[r]);
      }
      float rs[4];
      for (int r = 0; r < 4; ++r) rs[r] = dpp_sum16(s0[r] + s1[r]);
      for (int r = 0; r < 4; ++r) l_i[r] = l_i[r] * alpha[r] + rs[r];
      for (int nt = 0; nt < 8; ++nt)
        for (int r = 0; r < 4; ++r) accv[nt][r] *= alpha[r];

      // ---- P: C-layout -> LDS -> A-layout (m120 transform) ----
      unsigned short* pw = Ps + wave * 640;
      for (int r = 0; r < 4; ++r) {
        int row = quad * 4 + r;
        pw[row * 40 + low]      = f2bf(s0[r]);
        pw[row * 40 + 16 + low] = f2bf(s1[r]);
      }
      short8 pa = *(const short8*)&pw[low * 40 + quad * 8];

      // ---- O += P V : 8 d-tiles ----
      for (int nt = 0; nt < 8; ++nt) {
        int d  = nt * 16 + low;
        int pb = (quad + (d >> 3)) & 3;
        short8 vf = *(const short8*)&Vtp[d * 40 + pb * 8];
        accv[nt] = __builtin_amdgcn_mfma_f32_16x16x32_bf16(pa, vf, accv[nt], 0, 0, 0);
      }
    }
  }

  // ---- merge odd-half partials into even-half, write out ----
  __syncthreads();                        // staging LDS dead; overlay becomes live
  if (half == 1) {
    float* om = Om + qt * 2112;           // 16 rows x 132 (pad) floats
    for (int nt = 0; nt < 8; ++nt)
      for (int r = 0; r < 4; ++r)
        om[(quad * 4 + r) * 132 + nt * 16 + low] = accv[nt][r];
    if (low == 0) {
      for (int r = 0; r < 4; ++r) {
        Ml[qt * 32 + quad * 4 + r]      = m_i[r];
        Ml[qt * 32 + 16 + quad * 4 + r] = l_i[r];
      }
    }
  }
  __syncthreads();
  if (half == 0) {
    float aA[4], aB[4], linv[4], mB[4], lB[4];
    for (int r = 0; r < 4; ++r) {
      mB[r] = Ml[qt * 32 + quad * 4 + r];
      lB[r] = Ml[qt * 32 + 16 + quad * 4 + r];
      float mN = fmaxf(m_i[r], mB[r]);
      aA[r] = EXP2F(m_i[r] - mN);
      aB[r] = EXP2F(mB[r] - mN);
      linv[r] = 1.f / (l_i[r] * aA[r] + lB[r] * aB[r]);
    }
    const float* om = Om + qt * 2112;
    float* ob = out + ((size_t)b * SEQ_T + q0) * HDIM;
    for (int nt = 0; nt < 8; ++nt)
      for (int r = 0; r < 4; ++r) {
        float o = accv[nt][r] * aA[r] + om[(quad * 4 + r) * 132 + nt * 16 + low] * aB[r];
        ob[(size_t)(quad * 4 + r) * HDIM + nt * 16 + low] = o * linv[r];
      }
  }
}

extern "C" void kernel_launch(void* const* d_in, const int* in_sizes, int n_in,
                              void* d_out, int out_size, void* d_ws, size_t ws_size,
                              hipStream_t stream) {
  const float* x = (const float*)d_in[0];
  float* out = (float*)d_out;
  dim3 grid(SEQ_T / 64, NB);
  dim3 block(512);
  hipLaunchKernelGGL(attn_causal_kernel, grid, block, 0, stream, x, out);
}

// Round 4
// 168.560 us; speedup vs baseline: 1.6427x; 1.6427x over previous
//
#include <hip/hip_runtime.h>

#define SEQ_T 2048
#define HDIM  128
#define NB    16

typedef __attribute__((ext_vector_type(8))) short short8;      // 8 bf16 (4 VGPRs)
typedef __attribute__((ext_vector_type(4))) float float4v;
typedef __attribute__((ext_vector_type(4))) unsigned int uint4v;

// native 2^x (v_exp_f32)
#define EXP2F(x) __builtin_amdgcn_exp2f(x)

// round-half-up fp32 -> bf16, pack pair into one u32
__device__ __forceinline__ unsigned int bfpack2(float a, float b) {
  unsigned int ua = __builtin_bit_cast(unsigned int, a);
  unsigned int ub = __builtin_bit_cast(unsigned int, b);
  return ((ua + 0x8000u) >> 16) | ((ub + 0x8000u) & 0xFFFF0000u);
}
__device__ __forceinline__ unsigned short f2bf(float a) {
  return (unsigned short)((__builtin_bit_cast(unsigned int, a) + 0x8000u) >> 16);
}

// 16-lane butterfly reductions via DPP (VALU-rate, no LDS pipe)
__device__ __forceinline__ float dpp_max16(float x) {
  int t;
  t = __builtin_amdgcn_mov_dpp(__builtin_bit_cast(int, x), 0xB1, 0xF, 0xF, true);
  x = fmaxf(x, __builtin_bit_cast(float, t));
  t = __builtin_amdgcn_mov_dpp(__builtin_bit_cast(int, x), 0x4E, 0xF, 0xF, true);
  x = fmaxf(x, __builtin_bit_cast(float, t));
  t = __builtin_amdgcn_mov_dpp(__builtin_bit_cast(int, x), 0x141, 0xF, 0xF, true);
  x = fmaxf(x, __builtin_bit_cast(float, t));
  t = __builtin_amdgcn_mov_dpp(__builtin_bit_cast(int, x), 0x140, 0xF, 0xF, true);
  x = fmaxf(x, __builtin_bit_cast(float, t));
  return x;
}
__device__ __forceinline__ float dpp_sum16(float x) {
  int t;
  t = __builtin_amdgcn_mov_dpp(__builtin_bit_cast(int, x), 0xB1, 0xF, 0xF, true);
  x += __builtin_bit_cast(float, t);
  t = __builtin_amdgcn_mov_dpp(__builtin_bit_cast(int, x), 0x4E, 0xF, 0xF, true);
  x += __builtin_bit_cast(float, t);
  t = __builtin_amdgcn_mov_dpp(__builtin_bit_cast(int, x), 0x141, 0xF, 0xF, true);
  x += __builtin_bit_cast(float, t);
  t = __builtin_amdgcn_mov_dpp(__builtin_bit_cast(int, x), 0x140, 0xF, 0xF, true);
  x += __builtin_bit_cast(float, t);
  return x;
}

// x layout: [B, T, 384] with k = [0,128), q = [128,256), v = [256,384)
// Block: 512 threads = 8 waves. Waves 0-3: q-tiles 0-3, EVEN kv tiles.
// Waves 4-7: q-tiles 0-3, ODD kv tiles. End-of-loop merge via LDS overlay.
// launch_bounds(512,4): VGPR budget 128 — (512,6)'s 85-reg budget spilled
// accumulator state to scratch (R3: WRITE_SIZE 16->44MB, dur 152->220us).
__global__ __launch_bounds__(512, 4) void attn_causal_kernel(const float* __restrict__ x,
                                                             float* __restrict__ out) {
  const int b    = blockIdx.y;
  const int qblk = (int)gridDim.x - 1 - (int)blockIdx.x;  // longest blocks dispatch first
  const int qb0  = qblk << 6;                             // 64 q-rows per block
  const int tid  = threadIdx.x;
  const int wave = tid >> 6;
  const int lane = tid & 63;
  const int low  = lane & 15;
  const int quad = lane >> 4;
  const int qt   = wave & 3;                              // q-tile within block
  const int half = wave >> 2;                             // kv parity
  const int q0   = qb0 + (qt << 4);

  // staging layout (48128 B total):
  __shared__ __align__(16) unsigned char smem[48128];
  unsigned short* Ks = (unsigned short*)smem;             // [2][32*136] bf16, 17408 B
  unsigned short* Vt = (unsigned short*)(smem + 17408);   // [2][128*40] bf16 transposed, 20480 B
  unsigned short* Ps = (unsigned short*)(smem + 37888);   // [8][16*40] bf16, 10240 B
  // merge overlay (only used after the loop, after a barrier):
  float* Om = (float*)smem;                               // [4][16*132] fp32, 33792 B
  float* Ml = (float*)(smem + 33792);                     // [4][32] m|l, 512 B

  const float* xb = x + (size_t)b * (SEQ_T * 3 * HDIM);

  // ---- Q fragments, pre-scaled by 128^-0.5 * log2(e) so softmax uses exp2 ----
  const float qs = 0.08838834764831845f * 1.4426950408889634f;
  short8 qa[4];
  {
    const float* qrow = xb + (size_t)(q0 + low) * 384 + 128;
    for (int kc = 0; kc < 4; ++kc) {
      float4v f0 = *(const float4v*)(qrow + kc * 32 + quad * 8);
      float4v f1 = *(const float4v*)(qrow + kc * 32 + quad * 8 + 4);
      uint4v u = { bfpack2(f0[0] * qs, f0[1] * qs), bfpack2(f0[2] * qs, f0[3] * qs),
                   bfpack2(f1[0] * qs, f1[1] * qs), bfpack2(f1[2] * qs, f1[3] * qs) };
      qa[kc] = __builtin_bit_cast(short8, u);
    }
  }

  float4v accv[8];
  for (int i = 0; i < 8; ++i) accv[i] = (float4v){0.f, 0.f, 0.f, 0.f};
  float m_i[4] = {-1e30f, -1e30f, -1e30f, -1e30f};
  float l_i[4] = {0.f, 0.f, 0.f, 0.f};

  const int nsuper = qblk + 1;            // 64 kv rows (2 tiles) per super-iteration
  for (int s = 0; s < nsuper; ++s) {
    const int r0 = s << 6;
    __syncthreads();

    // ---- stage K: 64 rows x 128, fp32->bf16, 512 threads x 4 float4 ----
    for (int i = 0; i < 4; ++i) {
      int f   = tid + (i << 9);
      int row = f >> 5;                   // 0..63
      int c4  = (f & 31) << 2;
      float4v kf = *(const float4v*)(xb + (size_t)(r0 + row) * 384 + c4);
      *(uint2*)&Ks[(row >> 5) * 4352 + (row & 31) * 136 + c4] =
          make_uint2(bfpack2(kf[0], kf[1]), bfpack2(kf[2], kf[3]));
    }
    // ---- stage V transposed: thread owns 4kv x 4d block ----
    {
      int kb  = tid >> 5;                 // 0..15 (kv block of 4)
      int db  = tid & 31;                 // d block of 4
      int til = kb >> 3, kbl = kb & 7;
      const float* vbase = xb + (size_t)(r0 + 4 * kb) * 384 + 256 + 4 * db;
      float4v v0 = *(const float4v*)(vbase);
      float4v v1 = *(const float4v*)(vbase + 384);
      float4v v2 = *(const float4v*)(vbase + 768);
      float4v v3 = *(const float4v*)(vbase + 1152);
      unsigned short* vt = Vt + til * 5120;
      for (int j = 0; j < 4; ++j) {
        int d  = 4 * db + j;
        int pb = ((kbl >> 1) + (d >> 3)) & 3;   // 16B-block XOR swizzle
        *(uint2*)&vt[d * 40 + pb * 8 + (kbl & 1) * 4] =
            make_uint2(bfpack2(v0[j], v1[j]), bfpack2(v2[j], v3[j]));
      }
    }
    __syncthreads();

    const int c0 = r0 + (half << 5);
    if (c0 <= q0 + 15) {                  // wave-uniform causal skip
      const unsigned short* Ksp = Ks + half * 4352;
      const unsigned short* Vtp = Vt + half * 5120;

      // ---- S = Q K^T (pre-scaled): two 16-col tiles, K=128 = 4 mfma each ----
      float4v s0 = {0.f,0.f,0.f,0.f}, s1 = {0.f,0.f,0.f,0.f};
      for (int kc = 0; kc < 4; ++kc) {
        short8 kf0 = *(const short8*)&Ksp[low * 136 + kc * 32 + quad * 8];
        short8 kf1 = *(const short8*)&Ksp[(16 + low) * 136 + kc * 32 + quad * 8];
        s0 = __builtin_amdgcn_mfma_f32_16x16x32_bf16(qa[kc], kf0, s0, 0, 0, 0);
        s1 = __builtin_amdgcn_mfma_f32_16x16x32_bf16(qa[kc], kf1, s1, 0, 0, 0);
      }
      // ---- causal mask only on diagonal tiles (C-layout: col=lane&15, row=quad*4+r) ----
      if (c0 + 31 > q0) {
        for (int r = 0; r < 4; ++r) {
          int qrow = q0 + quad * 4 + r;
          s0[r] = (c0 + low      <= qrow) ? s0[r] : -1e30f;
          s1[r] = (c0 + 16 + low <= qrow) ? s1[r] : -1e30f;
        }
      }
      // ---- online softmax in exp2 domain, DPP reductions ----
      float rmax[4], alpha[4];
      for (int r = 0; r < 4; ++r) rmax[r] = dpp_max16(fmaxf(s0[r], s1[r]));
      for (int r = 0; r < 4; ++r) {
        float mn = fmaxf(m_i[r], rmax[r]);
        alpha[r] = EXP2F(m_i[r] - mn);
        m_i[r]   = mn;
      }
      for (int r = 0; r < 4; ++r) {
        s0[r] = EXP2F(s0[r] - m_i[r]);
        s1[r] = EXP2F(s1[r] - m_i[r]);
      }
      float rs[4];
      for (int r = 0; r < 4; ++r) rs[r] = dpp_sum16(s0[r] + s1[r]);
      for (int r = 0; r < 4; ++r) l_i[r] = l_i[r] * alpha[r] + rs[r];
      for (int nt = 0; nt < 8; ++nt)
        for (int r = 0; r < 4; ++r) accv[nt][r] *= alpha[r];

      // ---- P: C-layout -> LDS -> A-layout (m120 transform) ----
      unsigned short* pw = Ps + wave * 640;
      for (int r = 0; r < 4; ++r) {
        int row = quad * 4 + r;
        pw[row * 40 + low]      = f2bf(s0[r]);
        pw[row * 40 + 16 + low] = f2bf(s1[r]);
      }
      short8 pa = *(const short8*)&pw[low * 40 + quad * 8];

      // ---- O += P V : 8 d-tiles ----
      for (int nt = 0; nt < 8; ++nt) {
        int d  = nt * 16 + low;
        int pb = (quad + (d >> 3)) & 3;
        short8 vf = *(const short8*)&Vtp[d * 40 + pb * 8];
        accv[nt] = __builtin_amdgcn_mfma_f32_16x16x32_bf16(pa, vf, accv[nt], 0, 0, 0);
      }
    }
  }

  // ---- merge odd-half partials into even-half, write out ----
  __syncthreads();                        // staging LDS dead; overlay becomes live
  if (half == 1) {
    float* om = Om + qt * 2112;           // 16 rows x 132 (pad) floats
    for (int nt = 0; nt < 8; ++nt)
      for (int r = 0; r < 4; ++r)
        om[(quad * 4 + r) * 132 + nt * 16 + low] = accv[nt][r];
    if (low == 0) {
      for (int r = 0; r < 4; ++r) {
        Ml[qt * 32 + quad * 4 + r]      = m_i[r];
        Ml[qt * 32 + 16 + quad * 4 + r] = l_i[r];
      }
    }
  }
  __syncthreads();
  if (half == 0) {
    float aA[4], aB[4], linv[4], mB[4], lB[4];
    for (int r = 0; r < 4; ++r) {
      mB[r] = Ml[qt * 32 + quad * 4 + r];
      lB[r] = Ml[qt * 32 + 16 + quad * 4 + r];
      float mN = fmaxf(m_i[r], mB[r]);
      aA[r] = EXP2F(m_i[r] - mN);
      aB[r] = EXP2F(mB[r] - mN);
      linv[r] = 1.f / (l_i[r] * aA[r] + lB[r] * aB[r]);
    }
    const float* om = Om + qt * 2112;
    float* ob = out + ((size_t)b * SEQ_T + q0) * HDIM;
    for (int nt = 0; nt < 8; ++nt)
      for (int r = 0; r < 4; ++r) {
        float o = accv[nt][r] * aA[r] + om[(quad * 4 + r) * 132 + nt * 16 + low] * aB[r];
        ob[(size_t)(quad * 4 + r) * HDIM + nt * 16 + low] = o * linv[r];
      }
  }
}

extern "C" void kernel_launch(void* const* d_in, const int* in_sizes, int n_in,
                              void* d_out, int out_size, void* d_ws, size_t ws_size,
                              hipStream_t stream) {
  const float* x = (const float*)d_in[0];
  float* out = (float*)d_out;
  dim3 grid(SEQ_T / 64, NB);
  dim3 block(512);
  hipLaunchKernelGGL(attn_causal_kernel, grid, block, 0, stream, x, out);
}

// Round 5
// 161.855 us; speedup vs baseline: 1.7108x; 1.0414x over previous
//
#include <hip/hip_runtime.h>

#define SEQ_T 2048
#define HDIM  128
#define NB    16
#define NTILES (SEQ_T / 64)          // 32 kv-tiles of 64
#define TILE_SHORTS 8192             // 16 KB per tile (64x128 bf16)

typedef __attribute__((ext_vector_type(8))) short short8;      // 8 bf16 (4 VGPRs)
typedef __attribute__((ext_vector_type(4))) float float4v;
typedef __attribute__((ext_vector_type(4))) unsigned int uint4v;

#define EXP2F(x) __builtin_amdgcn_exp2f(x)

__device__ __forceinline__ unsigned int bfpack2(float a, float b) {
  unsigned int ua = __builtin_bit_cast(unsigned int, a);
  unsigned int ub = __builtin_bit_cast(unsigned int, b);
  return ((ua + 0x8000u) >> 16) | ((ub + 0x8000u) & 0xFFFF0000u);
}
__device__ __forceinline__ unsigned short f2bf(float a) {
  return (unsigned short)((__builtin_bit_cast(unsigned int, a) + 0x8000u) >> 16);
}

__device__ __forceinline__ float dpp_max16(float x) {
  int t;
  t = __builtin_amdgcn_mov_dpp(__builtin_bit_cast(int, x), 0xB1, 0xF, 0xF, true);
  x = fmaxf(x, __builtin_bit_cast(float, t));
  t = __builtin_amdgcn_mov_dpp(__builtin_bit_cast(int, x), 0x4E, 0xF, 0xF, true);
  x = fmaxf(x, __builtin_bit_cast(float, t));
  t = __builtin_amdgcn_mov_dpp(__builtin_bit_cast(int, x), 0x141, 0xF, 0xF, true);
  x = fmaxf(x, __builtin_bit_cast(float, t));
  t = __builtin_amdgcn_mov_dpp(__builtin_bit_cast(int, x), 0x140, 0xF, 0xF, true);
  x = fmaxf(x, __builtin_bit_cast(float, t));
  return x;
}
__device__ __forceinline__ float dpp_sum16(float x) {
  int t;
  t = __builtin_amdgcn_mov_dpp(__builtin_bit_cast(int, x), 0xB1, 0xF, 0xF, true);
  x += __builtin_bit_cast(float, t);
  t = __builtin_amdgcn_mov_dpp(__builtin_bit_cast(int, x), 0x4E, 0xF, 0xF, true);
  x += __builtin_bit_cast(float, t);
  t = __builtin_amdgcn_mov_dpp(__builtin_bit_cast(int, x), 0x141, 0xF, 0xF, true);
  x += __builtin_bit_cast(float, t);
  t = __builtin_amdgcn_mov_dpp(__builtin_bit_cast(int, x), 0x140, 0xF, 0xF, true);
  x += __builtin_bit_cast(float, t);
  return x;
}

// async 16B/lane global->LDS DMA; LDS image = wave-uniform base + lane*16
__device__ __forceinline__ void stage16(const unsigned short* g, unsigned short* l) {
  __builtin_amdgcn_global_load_lds(
      (const __attribute__((address_space(1))) unsigned int*)g,
      (__attribute__((address_space(3))) unsigned int*)l, 16, 0, 0);
}

// ============================ prepass ============================
// x [B,T,384] fp32 -> kbuf: per (b,tile): 64 rows x 16 units(16B), unit u of row r
// stored at linear unit r*16 + ((u+r)&15)  (so linear LDS image is swizzled).
// vbuf: V transposed: per (b,tile): 128 d x 8 units, unit u (=kv/8) of d-row
// stored at linear unit d*8 + ((u+d)&7).
__global__ __launch_bounds__(256) void prepass_kernel(const float* __restrict__ x,
                                                      unsigned short* __restrict__ kbuf,
                                                      unsigned short* __restrict__ vbuf) {
  const int n = blockIdx.x * 256 + threadIdx.x;   // 0 .. 16*32*1024-1
  const int b = n >> 15;
  const int t = (n >> 10) & 31;
  const int g = n & 1023;
  const float* xb = x + (size_t)b * (SEQ_T * 384);
  {   // K unit: r = g>>4, u = g&15 (u fastest -> coalesced 32B/lane reads)
    int r = g >> 4, u = g & 15;
    const float* src = xb + (size_t)(t * 64 + r) * 384 + u * 8;
    float4v a = *(const float4v*)src;
    float4v c = *(const float4v*)(src + 4);
    uint4v pk = { bfpack2(a[0], a[1]), bfpack2(a[2], a[3]),
                  bfpack2(c[0], c[1]), bfpack2(c[2], c[3]) };
    int dst = (n & ~1023) | (r * 16 + ((u + r) & 15));
    *(uint4v*)(kbuf + (size_t)dst * 8) = pk;
  }
  {   // V unit: u = g>>7, d = g&127 (d fastest -> coalesced column reads)
    int u = g >> 7, d = g & 127;
    const float* src = xb + (size_t)(t * 64 + u * 8) * 384 + 256 + d;
    uint4v pv = { bfpack2(src[0],    src[384]),
                  bfpack2(src[768],  src[1152]),
                  bfpack2(src[1536], src[1920]),
                  bfpack2(src[2304], src[2688]) };
    int dst = (n & ~1023) | (d * 8 + ((u + d) & 7));
    *(uint4v*)(vbuf + (size_t)dst * 8) = pv;
  }
}

// ============================ main kernel ============================
// Block: 512 thr = 8 waves. Waves 0-3: q-tiles 0-3 even kv half; 4-7: odd half.
__global__ __launch_bounds__(512, 4) void attn_fast(const float* __restrict__ x,
                                                    const unsigned short* __restrict__ kbuf,
                                                    const unsigned short* __restrict__ vbuf,
                                                    float* __restrict__ out) {
  const int b    = blockIdx.y;
  const int qblk = (int)gridDim.x - 1 - (int)blockIdx.x;
  const int qb0  = qblk << 6;
  const int tid  = threadIdx.x;
  const int wave = tid >> 6;
  const int lane = tid & 63;
  const int low  = lane & 15;
  const int quad = lane >> 4;
  const int qt   = wave & 3;
  const int half = wave >> 2;
  const int q0   = qb0 + (qt << 4);

  __shared__ __align__(16) unsigned char smem[43008];
  unsigned short* Ks = (unsigned short*)smem;            // 16 KB: 64 rows x 128 shorts, swizzled
  unsigned short* Vt = (unsigned short*)(smem + 16384);  // 16 KB: 128 d x 64 shorts, swizzled
  unsigned short* Ps = (unsigned short*)(smem + 32768);  // [8][16*40] bf16
  float* Om = (float*)smem;                              // overlay: [4][16*132] fp32
  float* Ml = (float*)(smem + 33792);                    // [4][32]

  const float* xb = x + (size_t)b * (SEQ_T * 3 * HDIM);
  const unsigned short* kt = kbuf + (size_t)b * NTILES * TILE_SHORTS;
  const unsigned short* vt = vbuf + (size_t)b * NTILES * TILE_SHORTS;

  // Q fragments, pre-scaled by 128^-0.5 * log2(e)
  const float qs = 0.08838834764831845f * 1.4426950408889634f;
  short8 qa[4];
  {
    const float* qrow = xb + (size_t)(q0 + low) * 384 + 128;
    for (int kc = 0; kc < 4; ++kc) {
      float4v f0 = *(const float4v*)(qrow + kc * 32 + quad * 8);
      float4v f1 = *(const float4v*)(qrow + kc * 32 + quad * 8 + 4);
      uint4v u = { bfpack2(f0[0] * qs, f0[1] * qs), bfpack2(f0[2] * qs, f0[3] * qs),
                   bfpack2(f1[0] * qs, f1[1] * qs), bfpack2(f1[2] * qs, f1[3] * qs) };
      qa[kc] = __builtin_bit_cast(short8, u);
    }
  }

  float4v accv[8];
  for (int i = 0; i < 8; ++i) accv[i] = (float4v){0.f, 0.f, 0.f, 0.f};
  float m_i[4] = {-1e30f, -1e30f, -1e30f, -1e30f};
  float l_i[4] = {0.f, 0.f, 0.f, 0.f};

  const int nsuper = qblk + 1;
  for (int s = 0; s < nsuper; ++s) {
    __syncthreads();                       // LDS free (prev readers done)
    {  // stage 16KB K + 16KB V: 4 async DMA instr per wave, no VALU convert
      const unsigned short* ksrc = kt + (size_t)s * TILE_SHORTS;
      const unsigned short* vsrc = vt + (size_t)s * TILE_SHORTS;
      int ch = wave * 2;                   // two 1KB chunks per wave per tensor
      stage16(ksrc + (size_t)ch * 512 + lane * 8,       Ks + ch * 512);
      stage16(ksrc + (size_t)(ch + 1) * 512 + lane * 8, Ks + (ch + 1) * 512);
      stage16(vsrc + (size_t)ch * 512 + lane * 8,       Vt + ch * 512);
      stage16(vsrc + (size_t)(ch + 1) * 512 + lane * 8, Vt + (ch + 1) * 512);
    }
    __syncthreads();                       // drains vmcnt -> tile ready

    const int c0 = (s << 6) + (half << 5);
    if (c0 <= q0 + 15) {                   // wave-uniform causal skip
      // ---- S = Q K^T: rows Ra (s0) / Rb (s1), swizzled unit = (kc*4+quad+R)&15
      const int Ra = (half << 5) + low;
      const int Rb = Ra + 16;
      float4v s0 = {0.f,0.f,0.f,0.f}, s1 = {0.f,0.f,0.f,0.f};
      for (int kc = 0; kc < 4; ++kc) {
        short8 kf0 = *(const short8*)&Ks[Ra * 128 + (((kc * 4 + quad) + Ra) & 15) * 8];
        short8 kf1 = *(const short8*)&Ks[Rb * 128 + (((kc * 4 + quad) + Rb) & 15) * 8];
        s0 = __builtin_amdgcn_mfma_f32_16x16x32_bf16(qa[kc], kf0, s0, 0, 0, 0);
        s1 = __builtin_amdgcn_mfma_f32_16x16x32_bf16(qa[kc], kf1, s1, 0, 0, 0);
      }
      // ---- causal mask on diagonal tiles (C-layout: col=lane&15, row=quad*4+r)
      if (c0 + 31 > q0) {
        for (int r = 0; r < 4; ++r) {
          int qrow = q0 + quad * 4 + r;
          s0[r] = (c0 + low      <= qrow) ? s0[r] : -1e30f;
          s1[r] = (c0 + 16 + low <= qrow) ? s1[r] : -1e30f;
        }
      }
      // ---- online softmax (exp2 domain), DPP reductions
      float rmax[4], alpha[4];
      for (int r = 0; r < 4; ++r) rmax[r] = dpp_max16(fmaxf(s0[r], s1[r]));
      for (int r = 0; r < 4; ++r) {
        float mn = fmaxf(m_i[r], rmax[r]);
        alpha[r] = EXP2F(m_i[r] - mn);
        m_i[r]   = mn;
      }
      for (int r = 0; r < 4; ++r) {
        s0[r] = EXP2F(s0[r] - m_i[r]);
        s1[r] = EXP2F(s1[r] - m_i[r]);
      }
      float rs[4];
      for (int r = 0; r < 4; ++r) rs[r] = dpp_sum16(s0[r] + s1[r]);
      for (int r = 0; r < 4; ++r) l_i[r] = l_i[r] * alpha[r] + rs[r];
      for (int nt = 0; nt < 8; ++nt)
        for (int r = 0; r < 4; ++r) accv[nt][r] *= alpha[r];

      // ---- P: C-layout -> LDS -> A-layout
      unsigned short* pw = Ps + wave * 640;
      for (int r = 0; r < 4; ++r) {
        int row = quad * 4 + r;
        pw[row * 40 + low]      = f2bf(s0[r]);
        pw[row * 40 + 16 + low] = f2bf(s1[r]);
      }
      short8 pa = *(const short8*)&pw[low * 40 + quad * 8];

      // ---- O += P V: V^T swizzled unit = (half*4+quad+d)&7
      const int ub = (half << 2) + quad;
      for (int nt = 0; nt < 8; ++nt) {
        int d = nt * 16 + low;
        short8 vf = *(const short8*)&Vt[d * 64 + ((ub + d) & 7) * 8];
        accv[nt] = __builtin_amdgcn_mfma_f32_16x16x32_bf16(pa, vf, accv[nt], 0, 0, 0);
      }
    }
  }

  // ---- merge odd-half into even-half, write out
  __syncthreads();
  if (half == 1) {
    float* om = Om + qt * 2112;
    for (int nt = 0; nt < 8; ++nt)
      for (int r = 0; r < 4; ++r)
        om[(quad * 4 + r) * 132 + nt * 16 + low] = accv[nt][r];
    if (low == 0) {
      for (int r = 0; r < 4; ++r) {
        Ml[qt * 32 + quad * 4 + r]      = m_i[r];
        Ml[qt * 32 + 16 + quad * 4 + r] = l_i[r];
      }
    }
  }
  __syncthreads();
  if (half == 0) {
    float aA[4], aB[4], linv[4];
    for (int r = 0; r < 4; ++r) {
      float mB = Ml[qt * 32 + quad * 4 + r];
      float lB = Ml[qt * 32 + 16 + quad * 4 + r];
      float mN = fmaxf(m_i[r], mB);
      aA[r] = EXP2F(m_i[r] - mN);
      aB[r] = EXP2F(mB - mN);
      linv[r] = 1.f / (l_i[r] * aA[r] + lB * aB[r]);
    }
    const float* om = Om + qt * 2112;
    float* ob = out + ((size_t)b * SEQ_T + q0) * HDIM;
    for (int nt = 0; nt < 8; ++nt)
      for (int r = 0; r < 4; ++r) {
        float o = accv[nt][r] * aA[r] + om[(quad * 4 + r) * 132 + nt * 16 + low] * aB[r];
        ob[(size_t)(quad * 4 + r) * HDIM + nt * 16 + low] = o * linv[r];
      }
  }
}

// ============================ fallback (R4) — used only if ws too small ============
__global__ __launch_bounds__(512, 4) void attn_fb(const float* __restrict__ x,
                                                  float* __restrict__ out) {
  const int b    = blockIdx.y;
  const int qblk = (int)gridDim.x - 1 - (int)blockIdx.x;
  const int qb0  = qblk << 6;
  const int tid  = threadIdx.x;
  const int wave = tid >> 6;
  const int lane = tid & 63;
  const int low  = lane & 15;
  const int quad = lane >> 4;
  const int qt   = wave & 3;
  const int half = wave >> 2;
  const int q0   = qb0 + (qt << 4);
  __shared__ __align__(16) unsigned char smem[48128];
  unsigned short* Ks = (unsigned short*)smem;
  unsigned short* Vt = (unsigned short*)(smem + 17408);
  unsigned short* Ps = (unsigned short*)(smem + 37888);
  float* Om = (float*)smem;
  float* Ml = (float*)(smem + 33792);
  const float* xb = x + (size_t)b * (SEQ_T * 3 * HDIM);
  const float qs = 0.08838834764831845f * 1.4426950408889634f;
  short8 qa[4];
  {
    const float* qrow = xb + (size_t)(q0 + low) * 384 + 128;
    for (int kc = 0; kc < 4; ++kc) {
      float4v f0 = *(const float4v*)(qrow + kc * 32 + quad * 8);
      float4v f1 = *(const float4v*)(qrow + kc * 32 + quad * 8 + 4);
      uint4v u = { bfpack2(f0[0] * qs, f0[1] * qs), bfpack2(f0[2] * qs, f0[3] * qs),
                   bfpack2(f1[0] * qs, f1[1] * qs), bfpack2(f1[2] * qs, f1[3] * qs) };
      qa[kc] = __builtin_bit_cast(short8, u);
    }
  }
  float4v accv[8];
  for (int i = 0; i < 8; ++i) accv[i] = (float4v){0.f, 0.f, 0.f, 0.f};
  float m_i[4] = {-1e30f, -1e30f, -1e30f, -1e30f};
  float l_i[4] = {0.f, 0.f, 0.f, 0.f};
  const int nsuper = qblk + 1;
  for (int s = 0; s < nsuper; ++s) {
    const int r0 = s << 6;
    __syncthreads();
    for (int i = 0; i < 4; ++i) {
      int f = tid + (i << 9);
      int row = f >> 5;
      int c4 = (f & 31) << 2;
      float4v kf = *(const float4v*)(xb + (size_t)(r0 + row) * 384 + c4);
      *(uint2*)&Ks[(row >> 5) * 4352 + (row & 31) * 136 + c4] =
          make_uint2(bfpack2(kf[0], kf[1]), bfpack2(kf[2], kf[3]));
    }
    {
      int kb = tid >> 5, db = tid & 31;
      int til = kb >> 3, kbl = kb & 7;
      const float* vbase = xb + (size_t)(r0 + 4 * kb) * 384 + 256 + 4 * db;
      float4v v0 = *(const float4v*)(vbase);
      float4v v1 = *(const float4v*)(vbase + 384);
      float4v v2 = *(const float4v*)(vbase + 768);
      float4v v3 = *(const float4v*)(vbase + 1152);
      unsigned short* vv = Vt + til * 5120;
      for (int j = 0; j < 4; ++j) {
        int d = 4 * db + j;
        int pb = ((kbl >> 1) + (d >> 3)) & 3;
        *(uint2*)&vv[d * 40 + pb * 8 + (kbl & 1) * 4] =
            make_uint2(bfpack2(v0[j], v1[j]), bfpack2(v2[j], v3[j]));
      }
    }
    __syncthreads();
    const int c0 = r0 + (half << 5);
    if (c0 <= q0 + 15) {
      const unsigned short* Ksp = Ks + half * 4352;
      const unsigned short* Vtp = Vt + half * 5120;
      float4v s0 = {0.f,0.f,0.f,0.f}, s1 = {0.f,0.f,0.f,0.f};
      for (int kc = 0; kc < 4; ++kc) {
        short8 kf0 = *(const short8*)&Ksp[low * 136 + kc * 32 + quad * 8];
        short8 kf1 = *(const short8*)&Ksp[(16 + low) * 136 + kc * 32 + quad * 8];
        s0 = __builtin_amdgcn_mfma_f32_16x16x32_bf16(qa[kc], kf0, s0, 0, 0, 0);
        s1 = __builtin_amdgcn_mfma_f32_16x16x32_bf16(qa[kc], kf1, s1, 0, 0, 0);
      }
      if (c0 + 31 > q0) {
        for (int r = 0; r < 4; ++r) {
          int qrow = q0 + quad * 4 + r;
          s0[r] = (c0 + low      <= qrow) ? s0[r] : -1e30f;
          s1[r] = (c0 + 16 + low <= qrow) ? s1[r] : -1e30f;
        }
      }
      float rmax[4], alpha[4];
      for (int r = 0; r < 4; ++r) rmax[r] = dpp_max16(fmaxf(s0[r], s1[r]));
      for (int r = 0; r < 4; ++r) {
        float mn = fmaxf(m_i[r], rmax[r]);
        alpha[r] = EXP2F(m_i[r] - mn);
        m_i[r] = mn;
      }
      for (int r = 0; r < 4; ++r) {
        s0[r] = EXP2F(s0[r] - m_i[r]);
        s1[r] = EXP2F(s1[r] - m_i[r]);
      }
      float rs[4];
      for (int r = 0; r < 4; ++r) rs[r] = dpp_sum16(s0[r] + s1[r]);
      for (int r = 0; r < 4; ++r) l_i[r] = l_i[r] * alpha[r] + rs[r];
      for (int nt = 0; nt < 8; ++nt)
        for (int r = 0; r < 4; ++r) accv[nt][r] *= alpha[r];
      unsigned short* pw = Ps + wave * 640;
      for (int r = 0; r < 4; ++r) {
        int row = quad * 4 + r;
        pw[row * 40 + low]      = f2bf(s0[r]);
        pw[row * 40 + 16 + low] = f2bf(s1[r]);
      }
      short8 pa = *(const short8*)&pw[low * 40 + quad * 8];
      for (int nt = 0; nt < 8; ++nt) {
        int d = nt * 16 + low;
        int pb = (quad + (d >> 3)) & 3;
        short8 vf = *(const short8*)&Vtp[d * 40 + pb * 8];
        accv[nt] = __builtin_amdgcn_mfma_f32_16x16x32_bf16(pa, vf, accv[nt], 0, 0, 0);
      }
    }
  }
  __syncthreads();
  if (half == 1) {
    float* om = Om + qt * 2112;
    for (int nt = 0; nt < 8; ++nt)
      for (int r = 0; r < 4; ++r)
        om[(quad * 4 + r) * 132 + nt * 16 + low] = accv[nt][r];
    if (low == 0) {
      for (int r = 0; r < 4; ++r) {
        Ml[qt * 32 + quad * 4 + r]      = m_i[r];
        Ml[qt * 32 + 16 + quad * 4 + r] = l_i[r];
      }
    }
  }
  __syncthreads();
  if (half == 0) {
    float aA[4], aB[4], linv[4];
    for (int r = 0; r < 4; ++r) {
      float mB = Ml[qt * 32 + quad * 4 + r];
      float lB = Ml[qt * 32 + 16 + quad * 4 + r];
      float mN = fmaxf(m_i[r], mB);
      aA[r] = EXP2F(m_i[r] - mN);
      aB[r] = EXP2F(mB - mN);
      linv[r] = 1.f / (l_i[r] * aA[r] + lB * aB[r]);
    }
    const float* om = Om + qt * 2112;
    float* ob = out + ((size_t)b * SEQ_T + q0) * HDIM;
    for (int nt = 0; nt < 8; ++nt)
      for (int r = 0; r < 4; ++r) {
        float o = accv[nt][r] * aA[r] + om[(quad * 4 + r) * 132 + nt * 16 + low] * aB[r];
        ob[(size_t)(quad * 4 + r) * HDIM + nt * 16 + low] = o * linv[r];
      }
  }
}

extern "C" void kernel_launch(void* const* d_in, const int* in_sizes, int n_in,
                              void* d_out, int out_size, void* d_ws, size_t ws_size,
                              hipStream_t stream) {
  const float* x = (const float*)d_in[0];
  float* out = (float*)d_out;
  const size_t need = (size_t)NB * NTILES * TILE_SHORTS * 2 * sizeof(unsigned short); // 16 MB
  if (ws_size >= need) {
    unsigned short* kbuf = (unsigned short*)d_ws;
    unsigned short* vbuf = kbuf + (size_t)NB * NTILES * TILE_SHORTS;
    hipLaunchKernelGGL(prepass_kernel, dim3(NB * NTILES * 1024 / 256), dim3(256), 0, stream,
                       x, kbuf, vbuf);
    hipLaunchKernelGGL(attn_fast, dim3(SEQ_T / 64, NB), dim3(512), 0, stream,
                       x, kbuf, vbuf, out);
  } else {
    hipLaunchKernelGGL(attn_fb, dim3(SEQ_T / 64, NB), dim3(512), 0, stream, x, out);
  }
}